// Round 4
// baseline (336.234 us; speedup 1.0000x reference)
//
#include <hip/hip_runtime.h>

// EfConv forward, CSR-based (no fp32 atomics), fp16 edge/node payloads:
//   1. t = fp16(node_feat @ W^T)  (+ fused: zero deg)   [N,64] halves
//   2. deg[d] = #edges with dst==d   (int atomics, int4-vectorized)
//   3. offsets = exclusive_scan(deg) (3-kernel scan)
//   4. permute: pos=cursor[dst[e]]++; srcs[pos]=src[e]; efs[pos][:]=fp16(ef[e][:])
//      (16B NT scatter per edge; ef VALUES reordered so aggregate never gathers ef)
//   5. aggregate: per node n (one wave, lanes=o), 16-deep masked gather chains:
//        out[n,k,o] = b[o] + sum_{j in row n} efs[j,k] * t[srcs[j],o]   (fp32 accum)
//      srcs/efs reads are wave-uniform (scalar path); only the fp16 t row is a gather.
//      out written with NONTEMPORAL stores (write-once stream).
// (Resubmission of R3 source — R3 bench was an infra failure, no signal.)

#define FEATS 64
#define EDGE_DIM 8

typedef _Float16 half8 __attribute__((ext_vector_type(8)));

// ---- Kernel 1: t[n][o] = fp16(sum_i nf[n][i] * W[o][i]); also zeroes deg ----
__global__ void __launch_bounds__(256) transform_kernel(
    const float* __restrict__ nf, const float* __restrict__ W,
    _Float16* __restrict__ t, int* __restrict__ deg, int n_nodes)
{
    __shared__ float sWt[FEATS * 65];
    __shared__ float srow[4][FEATS];
    const int tid = threadIdx.x;

    int gid = blockIdx.x * 256 + tid;
    if (gid < n_nodes) deg[gid] = 0;

    #pragma unroll
    for (int base = 0; base < FEATS * FEATS; base += 256) {
        int idx = base + tid;
        int o = idx >> 6;
        int i = idx & 63;
        sWt[i * 65 + o] = W[idx];
    }

    const int r = tid >> 6;
    const int o = tid & 63;
    const int node = blockIdx.x * 4 + r;
    if (node < n_nodes) srow[r][o] = nf[(long)node * FEATS + o];
    __syncthreads();

    if (node >= n_nodes) return;
    float sum = 0.f;
    #pragma unroll
    for (int i = 0; i < FEATS; i++)
        sum += srow[r][i] * sWt[i * 65 + o];
    t[(long)node * FEATS + o] = (_Float16)sum;   // single rounding, fp32 accumulate
}

// ---- Kernel 2: histogram of dst (4 edges/thread) ----
__global__ void __launch_bounds__(256) hist_kernel(
    const int* __restrict__ dst, int* __restrict__ deg, int n_edges)
{
    int i4 = (blockIdx.x * 256 + threadIdx.x) * 4;
    if (i4 + 3 < n_edges) {
        int4 d = *(const int4*)(dst + i4);
        atomicAdd(&deg[d.x], 1);
        atomicAdd(&deg[d.y], 1);
        atomicAdd(&deg[d.z], 1);
        atomicAdd(&deg[d.w], 1);
    } else {
        for (int e = i4; e < n_edges; ++e) atomicAdd(&deg[dst[e]], 1);
    }
}

// ---- Kernel 3a: per-block partial sums of deg ----
__global__ void __launch_bounds__(256) partials_kernel(
    const int* __restrict__ deg, int* __restrict__ partials, int n)
{
    __shared__ int s[256];
    int i = blockIdx.x * 256 + threadIdx.x;
    s[threadIdx.x] = (i < n) ? deg[i] : 0;
    __syncthreads();
    for (int off = 128; off > 0; off >>= 1) {
        if (threadIdx.x < off) s[threadIdx.x] += s[threadIdx.x + off];
        __syncthreads();
    }
    if (threadIdx.x == 0) partials[blockIdx.x] = s[0];
}

// ---- Kernel 3b: exclusive scan of partials (single block, nb <= 256) ----
__global__ void __launch_bounds__(256) scan_partials_kernel(
    const int* __restrict__ partials, int* __restrict__ pscan, int nb)
{
    __shared__ int s[256];
    int tid = threadIdx.x;
    s[tid] = (tid < nb) ? partials[tid] : 0;
    for (int off = 1; off < 256; off <<= 1) {
        __syncthreads();
        int x = (tid >= off) ? s[tid - off] : 0;
        __syncthreads();
        s[tid] += x;
    }
    __syncthreads();
    pscan[tid] = (tid == 0) ? 0 : s[tid - 1];
}

// ---- Kernel 3c: block-local exclusive scan + add partial offset ----
__global__ void __launch_bounds__(256) scan_addback_kernel(
    const int* __restrict__ deg, const int* __restrict__ pscan,
    int* __restrict__ offsets, int* __restrict__ cursor,
    int n, int n_edges)
{
    __shared__ int s[256];
    int tid = threadIdx.x;
    int i = blockIdx.x * 256 + tid;
    int v = (i < n) ? deg[i] : 0;
    s[tid] = v;
    for (int off = 1; off < 256; off <<= 1) {
        __syncthreads();
        int x = (tid >= off) ? s[tid - off] : 0;
        __syncthreads();
        s[tid] += x;
    }
    __syncthreads();
    if (i < n) {
        int excl = pscan[blockIdx.x] + s[tid] - v;   // inclusive - self = exclusive
        offsets[i] = excl;
        cursor[i]  = excl;
    }
    if (blockIdx.x == 0 && tid == 0) offsets[n] = n_edges;
}

// ---- Kernel 4: permute edges AND fp16 ef rows into dst-sorted order ----
__global__ void __launch_bounds__(256) permute_ef_kernel(
    const int* __restrict__ src, const int* __restrict__ dst,
    const float* __restrict__ ef, int* __restrict__ cursor,
    int* __restrict__ srcs, half8* __restrict__ efs, int n_edges)
{
    int i4 = (blockIdx.x * 256 + threadIdx.x) * 4;
    if (i4 + 3 < n_edges) {
        int4 s = *(const int4*)(src + i4);
        int4 d = *(const int4*)(dst + i4);
        const float4* q = (const float4*)(ef + (long)i4 * EDGE_DIM);
        // 4 independent atomics in flight first
        int p0 = atomicAdd(&cursor[d.x], 1);
        int p1 = atomicAdd(&cursor[d.y], 1);
        int p2 = atomicAdd(&cursor[d.z], 1);
        int p3 = atomicAdd(&cursor[d.w], 1);
        #pragma unroll
        for (int u = 0; u < 4; u++) {
            float4 a = q[2 * u], c = q[2 * u + 1];
            half8 h;
            h[0] = (_Float16)a.x; h[1] = (_Float16)a.y;
            h[2] = (_Float16)a.z; h[3] = (_Float16)a.w;
            h[4] = (_Float16)c.x; h[5] = (_Float16)c.y;
            h[6] = (_Float16)c.z; h[7] = (_Float16)c.w;
            int p = (u == 0) ? p0 : (u == 1) ? p1 : (u == 2) ? p2 : p3;
            __builtin_nontemporal_store(h, &efs[p]);           // 16B NT scatter
        }
        __builtin_nontemporal_store(s.x, &srcs[p0]);
        __builtin_nontemporal_store(s.y, &srcs[p1]);
        __builtin_nontemporal_store(s.z, &srcs[p2]);
        __builtin_nontemporal_store(s.w, &srcs[p3]);
    } else {
        for (int e = i4; e < n_edges; ++e) {
            int p = atomicAdd(&cursor[dst[e]], 1);
            srcs[p] = src[e];
            const float* q = ef + (long)e * EDGE_DIM;
            half8 h;
            #pragma unroll
            for (int k = 0; k < EDGE_DIM; k++) h[k] = (_Float16)q[k];
            efs[p] = h;
        }
    }
}

// ---- Kernel 5: per-node aggregation, 16-deep chains, scalar fp16 ef ----
#define CHUNK 16

__global__ void __launch_bounds__(256) aggregate_seq_kernel(
    const _Float16* __restrict__ t, const half8* __restrict__ efs,
    const int* __restrict__ srcs, const int* __restrict__ offsets,
    const float* __restrict__ b, float* __restrict__ out, int n_nodes)
{
    const int node = __builtin_amdgcn_readfirstlane(
        (int)((blockIdx.x * 256 + threadIdx.x) >> 6));
    const int o = threadIdx.x & 63;
    if (node >= n_nodes) return;

    const int beg = offsets[node];
    const int end = offsets[node + 1];
    float acc[EDGE_DIM];
    #pragma unroll
    for (int k = 0; k < EDGE_DIM; k++) acc[k] = 0.f;

    if (end > beg) {
        const int last = end - 1;      // >= beg >= 0, so clamped idx always valid
        for (int j = beg; j < end; j += CHUNK) {
            int sidx[CHUNK];
            #pragma unroll
            for (int u = 0; u < CHUNK; u++) {
                int jj = j + u;
                sidx[u] = srcs[jj <= last ? jj : last];   // uniform clamp (scalar)
            }
            float tv[CHUNK];
            #pragma unroll
            for (int u = 0; u < CHUNK; u++)               // CHUNK gathers in flight
                tv[u] = (float)t[(long)sidx[u] * FEATS + o];
            #pragma unroll
            for (int u = 0; u < CHUNK; u++) {
                int jj = j + u;
                int ej = jj <= last ? jj : last;
                float tvm = (jj <= last) ? tv[u] : 0.f;   // mask tail
                half8 row = efs[ej];                      // uniform 16B (scalar path)
                #pragma unroll
                for (int k = 0; k < EDGE_DIM; k++)
                    acc[k] += (float)row[k] * tvm;
            }
        }
    }

    const float bo = b[o];
    float* op = out + (long)node * (EDGE_DIM * FEATS) + o;
    #pragma unroll
    for (int k = 0; k < EDGE_DIM; k++)
        __builtin_nontemporal_store(acc[k] + bo, op + k * FEATS);
}

extern "C" void kernel_launch(void* const* d_in, const int* in_sizes, int n_in,
                              void* d_out, int out_size, void* d_ws, size_t ws_size,
                              hipStream_t stream) {
    const float* node_feat = (const float*)d_in[0];
    const float* edge_feat = (const float*)d_in[1];
    const float* W         = (const float*)d_in[2];
    const float* b         = (const float*)d_in[3];
    const int*   src       = (const int*)d_in[4];
    const int*   dst       = (const int*)d_in[5];
    float* out = (float*)d_out;

    const int n_nodes = in_sizes[0] / FEATS;
    const int n_edges = in_sizes[4];
    const int nb_nodes = (n_nodes + 255) / 256;        // blocks over nodes (<=256 required)
    const int nb_e4    = (n_edges + 1023) / 1024;      // 4 edges per thread

    // workspace layout (4B units)
    int* w = (int*)d_ws;
    _Float16* t   = (_Float16*)w;                      // N*64 halves = N*32 ints
    int* deg      = w + (long)n_nodes * (FEATS / 2);   // N
    int* offsets  = deg + n_nodes;                     // N+1
    int* cursor   = offsets + n_nodes + 1;             // N
    int* partials = cursor + n_nodes;                  // 256
    int* pscan    = partials + 256;                    // 256
    int* srcs     = pscan + 256;                       // E
    uintptr_t ea  = ((uintptr_t)(srcs + n_edges) + 15) & ~(uintptr_t)15;
    half8* efs    = (half8*)ea;                        // E * 16B

    transform_kernel<<<(n_nodes + 3) / 4, 256, 0, stream>>>(node_feat, W, t, deg, n_nodes);
    hist_kernel<<<nb_e4, 256, 0, stream>>>(dst, deg, n_edges);
    partials_kernel<<<nb_nodes, 256, 0, stream>>>(deg, partials, n_nodes);
    scan_partials_kernel<<<1, 256, 0, stream>>>(partials, pscan, nb_nodes);
    scan_addback_kernel<<<nb_nodes, 256, 0, stream>>>(deg, pscan, offsets, cursor,
                                                      n_nodes, n_edges);
    permute_ef_kernel<<<nb_e4, 256, 0, stream>>>(src, dst, edge_feat, cursor,
                                                 srcs, efs, n_edges);

    const long total_ag = (long)n_nodes * 64;
    aggregate_seq_kernel<<<(int)((total_ag + 255) / 256), 256, 0, stream>>>(
        t, efs, srcs, offsets, b, out, n_nodes);
}

// Round 5
// 282.399 us; speedup vs baseline: 1.1906x; 1.1906x over previous
//
#include <hip/hip_runtime.h>

// EfConv forward, CSR-based, fp16 payloads, atomic-free permute:
//   1. t = fp16(node_feat @ W^T)  (+ fused: zero deg)   [N,64] halves
//   2. hist: rank[e] = deg[dst[e]]++   (int atomics; rank stored coalesced)
//   3. offsets = exclusive_scan(deg) (3-kernel scan)
//   4. permute (NO atomics): pos = offsets[dst[e]] + rank[e];
//      srcs[pos]=src[e]; efs[pos][:]=fp16(ef[e][:])   (plain stores -> L2 write-combine)
//   5. aggregate: per node n (one wave, lanes=o), 16-deep masked gather chains:
//        out[n,k,o] = b[o] + sum_{j in row n} efs[j,k] * t[srcs[j],o]   (fp32 accum)
//      srcs/efs reads are wave-uniform (scalar path); only the fp16 t row is a gather.
//      out (coalesced full-line stream) written with NONTEMPORAL stores.
// R4 lesson: NT on SCATTERED stores caused 4-5x write amplification (79MB vs 16MB).

#define FEATS 64
#define EDGE_DIM 8

typedef _Float16 half8 __attribute__((ext_vector_type(8)));

// ---- Kernel 1: t[n][o] = fp16(sum_i nf[n][i] * W[o][i]); also zeroes deg ----
__global__ void __launch_bounds__(256) transform_kernel(
    const float* __restrict__ nf, const float* __restrict__ W,
    _Float16* __restrict__ t, int* __restrict__ deg, int n_nodes)
{
    __shared__ float sWt[FEATS * 65];
    __shared__ float srow[4][FEATS];
    const int tid = threadIdx.x;

    int gid = blockIdx.x * 256 + tid;
    if (gid < n_nodes) deg[gid] = 0;

    #pragma unroll
    for (int base = 0; base < FEATS * FEATS; base += 256) {
        int idx = base + tid;
        int o = idx >> 6;
        int i = idx & 63;
        sWt[i * 65 + o] = W[idx];
    }

    const int r = tid >> 6;
    const int o = tid & 63;
    const int node = blockIdx.x * 4 + r;
    if (node < n_nodes) srow[r][o] = nf[(long)node * FEATS + o];
    __syncthreads();

    if (node >= n_nodes) return;
    float sum = 0.f;
    #pragma unroll
    for (int i = 0; i < FEATS; i++)
        sum += srow[r][i] * sWt[i * 65 + o];
    t[(long)node * FEATS + o] = (_Float16)sum;   // single rounding, fp32 accumulate
}

// ---- Kernel 2: histogram of dst; keep atomic return as within-dst rank ----
__global__ void __launch_bounds__(256) hist_kernel(
    const int* __restrict__ dst, int* __restrict__ deg,
    int* __restrict__ rank, int n_edges)
{
    int i4 = (blockIdx.x * 256 + threadIdx.x) * 4;
    if (i4 + 3 < n_edges) {
        int4 d = *(const int4*)(dst + i4);
        int4 r;
        r.x = atomicAdd(&deg[d.x], 1);
        r.y = atomicAdd(&deg[d.y], 1);
        r.z = atomicAdd(&deg[d.z], 1);
        r.w = atomicAdd(&deg[d.w], 1);
        *(int4*)(rank + i4) = r;                 // coalesced
    } else {
        for (int e = i4; e < n_edges; ++e)
            rank[e] = atomicAdd(&deg[dst[e]], 1);
    }
}

// ---- Kernel 3a: per-block partial sums of deg ----
__global__ void __launch_bounds__(256) partials_kernel(
    const int* __restrict__ deg, int* __restrict__ partials, int n)
{
    __shared__ int s[256];
    int i = blockIdx.x * 256 + threadIdx.x;
    s[threadIdx.x] = (i < n) ? deg[i] : 0;
    __syncthreads();
    for (int off = 128; off > 0; off >>= 1) {
        if (threadIdx.x < off) s[threadIdx.x] += s[threadIdx.x + off];
        __syncthreads();
    }
    if (threadIdx.x == 0) partials[blockIdx.x] = s[0];
}

// ---- Kernel 3b: exclusive scan of partials (single block, nb <= 256) ----
__global__ void __launch_bounds__(256) scan_partials_kernel(
    const int* __restrict__ partials, int* __restrict__ pscan, int nb)
{
    __shared__ int s[256];
    int tid = threadIdx.x;
    s[tid] = (tid < nb) ? partials[tid] : 0;
    for (int off = 1; off < 256; off <<= 1) {
        __syncthreads();
        int x = (tid >= off) ? s[tid - off] : 0;
        __syncthreads();
        s[tid] += x;
    }
    __syncthreads();
    pscan[tid] = (tid == 0) ? 0 : s[tid - 1];
}

// ---- Kernel 3c: block-local exclusive scan + add partial offset ----
__global__ void __launch_bounds__(256) scan_addback_kernel(
    const int* __restrict__ deg, const int* __restrict__ pscan,
    int* __restrict__ offsets, int n, int n_edges)
{
    __shared__ int s[256];
    int tid = threadIdx.x;
    int i = blockIdx.x * 256 + tid;
    int v = (i < n) ? deg[i] : 0;
    s[tid] = v;
    for (int off = 1; off < 256; off <<= 1) {
        __syncthreads();
        int x = (tid >= off) ? s[tid - off] : 0;
        __syncthreads();
        s[tid] += x;
    }
    __syncthreads();
    if (i < n)
        offsets[i] = pscan[blockIdx.x] + s[tid] - v;   // inclusive - self = exclusive
    if (blockIdx.x == 0 && tid == 0) offsets[n] = n_edges;
}

// ---- Kernel 4: atomic-free permute of edges + fp16 ef rows ----
__global__ void __launch_bounds__(256) permute_ef_kernel(
    const int* __restrict__ src, const int* __restrict__ dst,
    const int* __restrict__ rank, const int* __restrict__ offsets,
    const float* __restrict__ ef,
    int* __restrict__ srcs, half8* __restrict__ efs, int n_edges)
{
    int i4 = (blockIdx.x * 256 + threadIdx.x) * 4;
    if (i4 + 3 < n_edges) {
        int4 s = *(const int4*)(src + i4);
        int4 d = *(const int4*)(dst + i4);
        int4 r = *(const int4*)(rank + i4);
        const float4* q = (const float4*)(ef + (long)i4 * EDGE_DIM);
        // 4 independent offsets gathers in flight (L2-resident, 200KB array)
        int p0 = offsets[d.x] + r.x;
        int p1 = offsets[d.y] + r.y;
        int p2 = offsets[d.z] + r.z;
        int p3 = offsets[d.w] + r.w;
        #pragma unroll
        for (int u = 0; u < 4; u++) {
            float4 a = q[2 * u], c = q[2 * u + 1];
            half8 h;
            h[0] = (_Float16)a.x; h[1] = (_Float16)a.y;
            h[2] = (_Float16)a.z; h[3] = (_Float16)a.w;
            h[4] = (_Float16)c.x; h[5] = (_Float16)c.y;
            h[6] = (_Float16)c.z; h[7] = (_Float16)c.w;
            int p = (u == 0) ? p0 : (u == 1) ? p1 : (u == 2) ? p2 : p3;
            efs[p] = h;                          // plain store: L2 write-combines
        }
        srcs[p0] = s.x; srcs[p1] = s.y; srcs[p2] = s.z; srcs[p3] = s.w;
    } else {
        for (int e = i4; e < n_edges; ++e) {
            int p = offsets[dst[e]] + rank[e];
            srcs[p] = src[e];
            const float* q = ef + (long)e * EDGE_DIM;
            half8 h;
            #pragma unroll
            for (int k = 0; k < EDGE_DIM; k++) h[k] = (_Float16)q[k];
            efs[p] = h;
        }
    }
}

// ---- Kernel 5: per-node aggregation, 16-deep chains, scalar fp16 ef ----
#define CHUNK 16

__global__ void __launch_bounds__(256) aggregate_seq_kernel(
    const _Float16* __restrict__ t, const half8* __restrict__ efs,
    const int* __restrict__ srcs, const int* __restrict__ offsets,
    const float* __restrict__ b, float* __restrict__ out, int n_nodes)
{
    const int node = __builtin_amdgcn_readfirstlane(
        (int)((blockIdx.x * 256 + threadIdx.x) >> 6));
    const int o = threadIdx.x & 63;
    if (node >= n_nodes) return;

    const int beg = offsets[node];
    const int end = offsets[node + 1];
    float acc[EDGE_DIM];
    #pragma unroll
    for (int k = 0; k < EDGE_DIM; k++) acc[k] = 0.f;

    if (end > beg) {
        const int last = end - 1;      // >= beg >= 0, so clamped idx always valid
        for (int j = beg; j < end; j += CHUNK) {
            int sidx[CHUNK];
            #pragma unroll
            for (int u = 0; u < CHUNK; u++) {
                int jj = j + u;
                sidx[u] = srcs[jj <= last ? jj : last];   // uniform clamp (scalar)
            }
            float tv[CHUNK];
            #pragma unroll
            for (int u = 0; u < CHUNK; u++)               // CHUNK gathers in flight
                tv[u] = (float)t[(long)sidx[u] * FEATS + o];
            #pragma unroll
            for (int u = 0; u < CHUNK; u++) {
                int jj = j + u;
                int ej = jj <= last ? jj : last;
                float tvm = (jj <= last) ? tv[u] : 0.f;   // mask tail
                half8 row = efs[ej];                      // uniform 16B (scalar path)
                #pragma unroll
                for (int k = 0; k < EDGE_DIM; k++)
                    acc[k] += (float)row[k] * tvm;
            }
        }
    }

    const float bo = b[o];
    float* op = out + (long)node * (EDGE_DIM * FEATS) + o;
    // out IS coalesced/full-line: NT is correct here (write-once stream)
    #pragma unroll
    for (int k = 0; k < EDGE_DIM; k++)
        __builtin_nontemporal_store(acc[k] + bo, op + k * FEATS);
}

extern "C" void kernel_launch(void* const* d_in, const int* in_sizes, int n_in,
                              void* d_out, int out_size, void* d_ws, size_t ws_size,
                              hipStream_t stream) {
    const float* node_feat = (const float*)d_in[0];
    const float* edge_feat = (const float*)d_in[1];
    const float* W         = (const float*)d_in[2];
    const float* b         = (const float*)d_in[3];
    const int*   src       = (const int*)d_in[4];
    const int*   dst       = (const int*)d_in[5];
    float* out = (float*)d_out;

    const int n_nodes = in_sizes[0] / FEATS;
    const int n_edges = in_sizes[4];
    const int nb_nodes = (n_nodes + 255) / 256;        // blocks over nodes (<=256 required)
    const int nb_e4    = (n_edges + 1023) / 1024;      // 4 edges per thread

    // workspace layout (4B units)
    int* w = (int*)d_ws;
    _Float16* t   = (_Float16*)w;                      // N*64 halves = N*32 ints
    int* deg      = w + (long)n_nodes * (FEATS / 2);   // N
    int* offsets  = deg + n_nodes;                     // N+1
    int* partials = offsets + n_nodes + 1;             // 256
    int* pscan    = partials + 256;                    // 256
    int* rank     = pscan + 256;                       // E
    int* srcs     = rank + n_edges;                    // E
    uintptr_t ea  = ((uintptr_t)(srcs + n_edges) + 15) & ~(uintptr_t)15;
    half8* efs    = (half8*)ea;                        // E * 16B

    transform_kernel<<<(n_nodes + 3) / 4, 256, 0, stream>>>(node_feat, W, t, deg, n_nodes);
    hist_kernel<<<nb_e4, 256, 0, stream>>>(dst, deg, rank, n_edges);
    partials_kernel<<<nb_nodes, 256, 0, stream>>>(deg, partials, n_nodes);
    scan_partials_kernel<<<1, 256, 0, stream>>>(partials, pscan, nb_nodes);
    scan_addback_kernel<<<nb_nodes, 256, 0, stream>>>(deg, pscan, offsets,
                                                      n_nodes, n_edges);
    permute_ef_kernel<<<nb_e4, 256, 0, stream>>>(src, dst, rank, offsets, edge_feat,
                                                 srcs, efs, n_edges);

    const long total_ag = (long)n_nodes * 64;
    aggregate_seq_kernel<<<(int)((total_ag + 255) / 256), 256, 0, stream>>>(
        t, efs, srcs, offsets, b, out, n_nodes);
}